// Round 7
// baseline (13.024 us; speedup 1.0000x reference)
//
#include <hip/hip_runtime.h>
#include <math.h>

// ---------------------------------------------------------------------------
// TripletLossAttribute — two kernels (empirically optimal structure on
// MI355X: in-kernel cross-XCD reduction costs more than a kernel boundary).
//
// kernel1: wave computes BOTH directed pairs (i,j),(j,i) over a QUARTER of k
// (512 elems) -> 8192 waves = 8/SIMD (max TLP, hides L2 latency).
// Pair map: p in [0,2048): i=p&63, j=(i+1+(p>>6))&63; d=32 double-writes are
// bit-identical. Diagonal never written; handled analytically in kernel2.
// seg(k) boundaries 341,682,1023,1364,1705: each 256-wide step crosses at
// most one -> one const-compare select per element.
//
// kernel2: reduce in sq-domain (sqrt monotone -> commutes with max/min),
// sqrt only the 2 per-row winners. Bit-identical to ref (same sq -> same
// sqrt). One float4 load per quarter per thread, 4-level 16-lane butterfly.
//
// ws layout: float pd[4][64][64] — quarter-k partial sq-sums (pre-sqrt).
// ---------------------------------------------------------------------------

__global__ __launch_bounds__(512) void pair_dist_kernel(
    const float* __restrict__ x,     // 64 x 2048
    const float* __restrict__ attr,  // 64 x 64 x 6
    float* __restrict__ pd)          // [4][64][64]
{
    const int w    = blockIdx.x * 8 + (threadIdx.x >> 6);  // 0..8191
    const int lane = threadIdx.x & 63;
    const int h    = w & 3;            // k-quarter
    const int p    = w >> 2;           // 0..2047
    const int i    = p & 63;
    const int dd   = 1 + (p >> 6);     // 1..32
    const int j    = (i + dd) & 63;

    const float4* __restrict__ xi = (const float4*)(x + i * 2048);
    const float4* __restrict__ xj = (const float4*)(x + j * 2048);
    const float2* __restrict__ aij = (const float2*)(attr + (i * 64 + j) * 6);
    const float2* __restrict__ aji = (const float2*)(attr + (j * 64 + i) * 6);

    const float2 bA = aij[0], bB = aij[1], bC = aij[2];
    const float2 cA = aji[0], cB = aji[1], cC = aji[2];
    const float b0 = bA.x * bA.x, b1 = bA.y * bA.y, b2 = bB.x * bB.x,
                b3 = bB.y * bB.y, b4 = bC.x * bC.x, b5 = bC.y * bC.y;
    const float c0 = cA.x * cA.x, c1 = cA.y * cA.y, c2 = cB.x * cB.x,
                c3 = cB.y * cB.y, c4 = cC.x * cC.x, c5 = cC.y * cC.y;

    float accI = 0.f, accJ = 0.f;

#define STEP_U2(T, WI, WJ)                                                    \
    {                                                                         \
        float4 vi = xi[(T) * 64 + lane], vj = xj[(T) * 64 + lane];            \
        float dx, d2;                                                         \
        dx = vj.x - vi.x; d2 = dx * dx; accI = fmaf(d2, (WI), accI); accJ = fmaf(d2, (WJ), accJ); \
        dx = vj.y - vi.y; d2 = dx * dx; accI = fmaf(d2, (WI), accI); accJ = fmaf(d2, (WJ), accJ); \
        dx = vj.z - vi.z; d2 = dx * dx; accI = fmaf(d2, (WI), accI); accJ = fmaf(d2, (WJ), accJ); \
        dx = vj.w - vi.w; d2 = dx * dx; accI = fmaf(d2, (WI), accI); accJ = fmaf(d2, (WJ), accJ); \
    }
#define STEP_B2(T, WIL, WIH, WJL, WJH, B)                                     \
    {                                                                         \
        const int k0 = ((T) * 64 + lane) * 4;                                 \
        float4 vi = xi[(T) * 64 + lane], vj = xj[(T) * 64 + lane];            \
        float dx, d2; bool lo;                                                \
        dx = vj.x - vi.x; d2 = dx * dx; lo = (k0 + 0 < (B));                  \
        accI = fmaf(d2, lo ? (WIL) : (WIH), accI); accJ = fmaf(d2, lo ? (WJL) : (WJH), accJ); \
        dx = vj.y - vi.y; d2 = dx * dx; lo = (k0 + 1 < (B));                  \
        accI = fmaf(d2, lo ? (WIL) : (WIH), accI); accJ = fmaf(d2, lo ? (WJL) : (WJH), accJ); \
        dx = vj.z - vi.z; d2 = dx * dx; lo = (k0 + 2 < (B));                  \
        accI = fmaf(d2, lo ? (WIL) : (WIH), accI); accJ = fmaf(d2, lo ? (WJL) : (WJH), accJ); \
        dx = vj.w - vi.w; d2 = dx * dx; lo = (k0 + 3 < (B));                  \
        accI = fmaf(d2, lo ? (WIL) : (WIH), accI); accJ = fmaf(d2, lo ? (WJL) : (WJH), accJ); \
    }

    switch (h) {
        case 0:                           // k in [0,512)
            STEP_U2(0, b0, c0);           // [0,256)     seg0
            STEP_B2(1, b0, b1, c0, c1, 341);
            break;
        case 1:                           // k in [512,1024)
            STEP_B2(2, b1, b2, c1, c2, 682);
            STEP_B2(3, b2, b3, c2, c3, 1023);
            break;
        case 2:                           // k in [1024,1536)
            STEP_U2(4, b3, c3);
            STEP_B2(5, b3, b4, c3, c4, 1364);
            break;
        default:                          // k in [1536,2048)
            STEP_B2(6, b4, b5, c4, c5, 1705);
            STEP_U2(7, b5, c5);
            break;
    }
#undef STEP_U2
#undef STEP_B2

#pragma unroll
    for (int off = 32; off; off >>= 1) {
        accI += __shfl_xor(accI, off);
        accJ += __shfl_xor(accJ, off);
    }

    if (lane == 0) {
        pd[h * 4096 + i * 64 + j] = accI;
        pd[h * 4096 + j * 64 + i] = accJ;
    }
}

// 1 block x 1024: thread t owns row r=t>>4, cols c0=(t&15)*4 .. +3.
// Reduce in sq-domain; sqrt only the two winners per row.
__global__ __launch_bounds__(1024) void loss_kernel(
    const float* __restrict__ pd,    // [4][64][64]
    const int*   __restrict__ tgt,   // 64
    float*       __restrict__ out)   // 1
{
    __shared__ float terms[64];
    const int t  = threadIdx.x;
    const int r  = t >> 4;
    const int c0 = (t & 15) * 4;

    const float4* __restrict__ pd4 = (const float4*)pd;
    const float4 q0 = pd4[t];
    const float4 q1 = pd4[1024 + t];
    const float4 q2 = pd4[2048 + t];
    const float4 q3 = pd4[3072 + t];
    const int    tr = tgt[r];

    float apq = -INFINITY, anq = INFINITY;   // sq-domain
#define ELEM(SC, C)                                                           \
    {                                                                         \
        const int c = (C);                                                    \
        /* diagonal never written by k1 (poison) -> analytic sq = 1e-12 */    \
        float s = (c == r) ? 1e-12f : fmaxf((SC), 1e-12f);                    \
        if (tgt[c] == tr) apq = fmaxf(apq, s); else anq = fminf(anq, s);      \
    }
    ELEM(q0.x + q1.x + q2.x + q3.x, c0 + 0);
    ELEM(q0.y + q1.y + q2.y + q3.y, c0 + 1);
    ELEM(q0.z + q1.z + q2.z + q3.z, c0 + 2);
    ELEM(q0.w + q1.w + q2.w + q3.w, c0 + 3);
#undef ELEM

    // 16-lane butterfly (xor 1,2,4,8 stays within the aligned 16-group)
#pragma unroll
    for (int off = 8; off; off >>= 1) {
        apq = fmaxf(apq, __shfl_xor(apq, off));
        anq = fminf(anq, __shfl_xor(anq, off));
    }
    // apq >= 1e-12 always (diagonal is positive-class); anq may be +inf
    // (row with no negatives) -> term = relu(-inf) = 0, matches ref
    if ((t & 15) == 0) terms[r] = fmaxf(sqrtf(apq) - sqrtf(anq) + 0.3f, 0.f);

    __syncthreads();

    if (t < 64) {
        float v = terms[t];
#pragma unroll
        for (int off = 32; off; off >>= 1) v += __shfl_xor(v, off);
        if (t == 0) out[0] = v * (1.0f / 64.0f);
    }
}

extern "C" void kernel_launch(void* const* d_in, const int* in_sizes, int n_in,
                              void* d_out, int out_size, void* d_ws, size_t ws_size,
                              hipStream_t stream) {
    const float* x    = (const float*)d_in[0];   // inputs (64,2048) f32
    const int*   tgt  = (const int*)d_in[1];     // targets (64,) i32
    const float* attr = (const float*)d_in[2];   // attention (64,64,6) f32
    float* out = (float*)d_out;
    float* pd  = (float*)d_ws;                   // 16384 floats

    pair_dist_kernel<<<1024, 512, 0, stream>>>(x, attr, pd);
    loss_kernel<<<1, 1024, 0, stream>>>(pd, tgt, out);
}

// Round 8
// 12.583 us; speedup vs baseline: 1.0350x; 1.0350x over previous
//
#include <hip/hip_runtime.h>
#include <math.h>

// ---------------------------------------------------------------------------
// TripletLossAttribute — two kernels (empirically the right structure: any
// in-kernel cross-XCD reduction costs more than a kernel boundary on MI355X).
//
// kernel1: wave computes BOTH directed pairs (i,j),(j,i) over HALF of k
// (shares (xi-xj)^2, halves x traffic, 4096 waves = 4/SIMD — measured
// optimum: 1/SIMD exposes L2 latency (r3), 8/SIMD adds ramp cost (r7)).
// Pair map: p in [0,2048): i=p&63, j=(i+1+(p>>6))&63; d=32 double-writes are
// bit-identical. Diagonal handled analytically in kernel2 (dist=1e-6).
// seg(k) boundaries 341,682,1023,1364,1705: each 256-wide chunk crosses at
// most one -> one const-compare select per element.
//
// kernel2: short critical path — one float4 load per half per thread,
// in-lane 4-wide minmax, 4-level 16-lane butterfly, then 64-term mean.
//
// ws layout: float pd[2][64][64] — k-half partial sq-sums (pre-sqrt).
// ---------------------------------------------------------------------------

__global__ __launch_bounds__(512) void pair_dist_kernel(
    const float* __restrict__ x,     // 64 x 2048
    const float* __restrict__ attr,  // 64 x 64 x 6
    float* __restrict__ pd)          // [2][64][64]
{
    const int w    = blockIdx.x * 8 + (threadIdx.x >> 6);  // 0..4095
    const int lane = threadIdx.x & 63;
    const int h    = w & 1;            // k-half
    const int p    = w >> 1;           // 0..2047
    const int i    = p & 63;
    const int dd   = 1 + (p >> 6);     // 1..32
    const int j    = (i + dd) & 63;

    const float4* __restrict__ xi = (const float4*)(x + i * 2048);
    const float4* __restrict__ xj = (const float4*)(x + j * 2048);
    const float2* __restrict__ aij = (const float2*)(attr + (i * 64 + j) * 6);
    const float2* __restrict__ aji = (const float2*)(attr + (j * 64 + i) * 6);

    const float2 bA = aij[0], bB = aij[1], bC = aij[2];
    const float2 cA = aji[0], cB = aji[1], cC = aji[2];
    const float b0 = bA.x * bA.x, b1 = bA.y * bA.y, b2 = bB.x * bB.x,
                b3 = bB.y * bB.y, b4 = bC.x * bC.x, b5 = bC.y * bC.y;
    const float c0 = cA.x * cA.x, c1 = cA.y * cA.y, c2 = cB.x * cB.x,
                c3 = cB.y * cB.y, c4 = cC.x * cC.x, c5 = cC.y * cC.y;

    float accI = 0.f, accJ = 0.f;

#define STEP_U2(T, WI, WJ)                                                    \
    {                                                                         \
        float4 vi = xi[(T) * 64 + lane], vj = xj[(T) * 64 + lane];            \
        float dx, d2;                                                         \
        dx = vj.x - vi.x; d2 = dx * dx; accI = fmaf(d2, (WI), accI); accJ = fmaf(d2, (WJ), accJ); \
        dx = vj.y - vi.y; d2 = dx * dx; accI = fmaf(d2, (WI), accI); accJ = fmaf(d2, (WJ), accJ); \
        dx = vj.z - vi.z; d2 = dx * dx; accI = fmaf(d2, (WI), accI); accJ = fmaf(d2, (WJ), accJ); \
        dx = vj.w - vi.w; d2 = dx * dx; accI = fmaf(d2, (WI), accI); accJ = fmaf(d2, (WJ), accJ); \
    }
#define STEP_B2(T, WIL, WIH, WJL, WJH, B)                                     \
    {                                                                         \
        const int k0 = ((T) * 64 + lane) * 4;                                 \
        float4 vi = xi[(T) * 64 + lane], vj = xj[(T) * 64 + lane];            \
        float dx, d2; bool lo;                                                \
        dx = vj.x - vi.x; d2 = dx * dx; lo = (k0 + 0 < (B));                  \
        accI = fmaf(d2, lo ? (WIL) : (WIH), accI); accJ = fmaf(d2, lo ? (WJL) : (WJH), accJ); \
        dx = vj.y - vi.y; d2 = dx * dx; lo = (k0 + 1 < (B));                  \
        accI = fmaf(d2, lo ? (WIL) : (WIH), accI); accJ = fmaf(d2, lo ? (WJL) : (WJH), accJ); \
        dx = vj.z - vi.z; d2 = dx * dx; lo = (k0 + 2 < (B));                  \
        accI = fmaf(d2, lo ? (WIL) : (WIH), accI); accJ = fmaf(d2, lo ? (WJL) : (WJH), accJ); \
        dx = vj.w - vi.w; d2 = dx * dx; lo = (k0 + 3 < (B));                  \
        accI = fmaf(d2, lo ? (WIL) : (WIH), accI); accJ = fmaf(d2, lo ? (WJL) : (WJH), accJ); \
    }

    if (h == 0) {                        // k in [0,1024)
        STEP_U2(0, b0, c0);
        STEP_B2(1, b0, b1, c0, c1, 341);
        STEP_B2(2, b1, b2, c1, c2, 682);
        STEP_B2(3, b2, b3, c2, c3, 1023);
    } else {                             // k in [1024,2048)
        STEP_U2(4, b3, c3);
        STEP_B2(5, b3, b4, c3, c4, 1364);
        STEP_B2(6, b4, b5, c4, c5, 1705);
        STEP_U2(7, b5, c5);
    }
#undef STEP_U2
#undef STEP_B2

#pragma unroll
    for (int off = 32; off; off >>= 1) {
        accI += __shfl_xor(accI, off);
        accJ += __shfl_xor(accJ, off);
    }

    if (lane == 0) {
        pd[h * 4096 + i * 64 + j] = accI;
        pd[h * 4096 + j * 64 + i] = accJ;
    }
}

// 1 block x 1024: thread t owns row r=t>>4, cols c0=(t&15)*4 .. +3.
__global__ __launch_bounds__(1024) void loss_kernel(
    const float* __restrict__ pd,    // [2][64][64]
    const int*   __restrict__ tgt,   // 64
    float*       __restrict__ out)   // 1
{
    __shared__ float terms[64];
    const int t  = threadIdx.x;
    const int r  = t >> 4;
    const int c0 = (t & 15) * 4;

    const float4* __restrict__ pd4 = (const float4*)pd;
    const float4 lo = pd4[t];          // half 0, row r, cols c0..c0+3
    const float4 hi = pd4[1024 + t];   // half 1
    const int    tr = tgt[r];

    float ap = -INFINITY, an = INFINITY;
#define ELEM(SC, C)                                                           \
    {                                                                         \
        const int c = (C);                                                    \
        float d = (c == r) ? 1e-6f : sqrtf(fmaxf((SC), 1e-12f));              \
        if (tgt[c] == tr) ap = fmaxf(ap, d); else an = fminf(an, d);          \
    }
    ELEM(lo.x + hi.x, c0 + 0);
    ELEM(lo.y + hi.y, c0 + 1);
    ELEM(lo.z + hi.z, c0 + 2);
    ELEM(lo.w + hi.w, c0 + 3);
#undef ELEM

    // 16-lane butterfly (xor 1,2,4,8 stays within the aligned 16-group)
#pragma unroll
    for (int off = 8; off; off >>= 1) {
        ap = fmaxf(ap, __shfl_xor(ap, off));
        an = fminf(an, __shfl_xor(an, off));
    }
    if ((t & 15) == 0) terms[r] = fmaxf(ap - an + 0.3f, 0.f);

    __syncthreads();

    if (t < 64) {
        float v = terms[t];
#pragma unroll
        for (int off = 32; off; off >>= 1) v += __shfl_xor(v, off);
        if (t == 0) out[0] = v * (1.0f / 64.0f);
    }
}

extern "C" void kernel_launch(void* const* d_in, const int* in_sizes, int n_in,
                              void* d_out, int out_size, void* d_ws, size_t ws_size,
                              hipStream_t stream) {
    const float* x    = (const float*)d_in[0];   // inputs (64,2048) f32
    const int*   tgt  = (const int*)d_in[1];     // targets (64,) i32
    const float* attr = (const float*)d_in[2];   // attention (64,64,6) f32
    float* out = (float*)d_out;
    float* pd  = (float*)d_ws;                   // 8192 floats

    pair_dist_kernel<<<512, 512, 0, stream>>>(x, attr, pd);
    loss_kernel<<<1, 1024, 0, stream>>>(pd, tgt, out);
}